// Round 2
// baseline (83.965 us; speedup 1.0000x reference)
//
#include <hip/hip_runtime.h>

#define EPS 1e-5f

// ws layout: bytes [0,64): double acc[8] = {sum[4], sumsq[4]}; bytes [1024, 1024+bsz*16): float z[bsz*4]
//
// Math: theta_i = mean(x[b,0,6i:6i+6,0:6]); c_i = cos(theta_i);
// CNOT chain (0,1)(1,2)(2,3)(3,0) is a classical XOR map, so
// z0=c1*c2*c3, z1=c0*c1, z2=c0*c1*c2, z3=c0*c1*c2*c3; then batchnorm over B.

__global__ __launch_bounds__(256) void qnat_stage1(const float* __restrict__ x,
                                                   float* __restrict__ z_out,
                                                   double* __restrict__ acc,
                                                   int bsz) {
    __shared__ float part[32][49];   // [img_local][slot 0..47], padded row to kill conflicts
    __shared__ float cArr[32][4];

    const int t = threadIdx.x;
    const int blockImg0 = blockIdx.x * 32;

    // Needed bytes per 4-row group (448 B): 8 float4 slots, each feeding exactly one row.
    // Even slot: cols 0-3 (sum 4); odd slot: cols 4-7 of which cols 4,5 needed (sum 2).
    // Slot pair (2m, 2m+1) belongs to row (g*4 + m)  =>  part[il][2*r], part[il][2*r+1].
    const int OFFS[8] = {0, 16, 112, 128, 224, 240, 336, 352};

    #pragma unroll
    for (int w = 0; w < 6; ++w) {
        const int idx = w * 256 + t;        // 0..1535  (32 images * 48 slots)
        const int il  = idx / 48;           // image local 0..31
        const int sl  = idx % 48;           // slot within image
        const int g   = sl >> 3;            // 4-row group 0..5
        const int i   = sl & 7;             // slot within group
        const int img = blockImg0 + il;
        float s = 0.0f;
        if (img < bsz) {
            const char* base = (const char*)x + (size_t)img * 3136 + g * 448 + OFFS[i];
            const float4 v = *reinterpret_cast<const float4*>(base);
            s = (i & 1) ? (v.x + v.y) : ((v.x + v.y) + (v.z + v.w));
        }
        part[il][sl] = s;
    }
    __syncthreads();

    if (t < 128) {
        const int il = t >> 2;
        const int p  = t & 3;
        float s = 0.0f;
        #pragma unroll
        for (int rr = 0; rr < 6; ++rr) {
            const int r = 6 * p + rr;
            s += part[il][2 * r] + part[il][2 * r + 1];
        }
        cArr[il][p] = cosf(s * (1.0f / 36.0f));
    }
    __syncthreads();

    float zv = 0.0f;
    if (t < 128) {
        const int il = t >> 2;
        const int p  = t & 3;
        const float c0 = cArr[il][0], c1 = cArr[il][1];
        const float c2 = cArr[il][2], c3 = cArr[il][3];
        const float t01 = c0 * c1;
        if      (p == 0) zv = c1 * c2 * c3;
        else if (p == 1) zv = t01;
        else if (p == 2) zv = t01 * c2;
        else             zv = t01 * c2 * c3;
        const int img = blockImg0 + il;
        if (img < bsz) z_out[img * 4 + p] = zv;   // coalesced 512B per block
        else           zv = 0.0f;
    }

    // block reduction of sum/sumsq per channel p (p = lane&3 for active threads)
    float s1 = zv, s2 = zv * zv;
    const int lane = t & 63;
    #pragma unroll
    for (int off = 32; off >= 4; off >>= 1) {
        s1 += __shfl_xor(s1, off, 64);
        s2 += __shfl_xor(s2, off, 64);
    }
    __shared__ float ls1[4][4], ls2[4][4];  // [wave][channel]
    const int wv = t >> 6;
    if (lane < 4) { ls1[wv][lane] = s1; ls2[wv][lane] = s2; }
    __syncthreads();
    if (t < 4) {
        const int k = t;
        const float t1 = (ls1[0][k] + ls1[1][k]) + (ls1[2][k] + ls1[3][k]);
        const float t2 = (ls2[0][k] + ls2[1][k]) + (ls2[2][k] + ls2[3][k]);
        atomicAdd(&acc[k],     (double)t1);
        atomicAdd(&acc[4 + k], (double)t2);
    }
}

__global__ __launch_bounds__(256) void qnat_stage2(const float* __restrict__ z,
                                                   const double* __restrict__ acc,
                                                   const float* __restrict__ gamma,
                                                   const float* __restrict__ beta,
                                                   float* __restrict__ out,
                                                   int bsz) {
    const double invB = 1.0 / (double)bsz;
    float mean[4], scale[4], bet[4];
    #pragma unroll
    for (int k = 0; k < 4; ++k) {
        const double m = acc[k] * invB;
        const double v = acc[4 + k] * invB - m * m;
        mean[k]  = (float)m;
        scale[k] = gamma[k] * rsqrtf((float)v + EPS);
        bet[k]   = beta[k];
    }
    const int t = blockIdx.x * blockDim.x + threadIdx.x;
    if (t < bsz) {
        const float4 zv = reinterpret_cast<const float4*>(z)[t];
        float4 o;
        o.x = (zv.x - mean[0]) * scale[0] + bet[0];
        o.y = (zv.y - mean[1]) * scale[1] + bet[1];
        o.z = (zv.z - mean[2]) * scale[2] + bet[2];
        o.w = (zv.w - mean[3]) * scale[3] + bet[3];
        reinterpret_cast<float4*>(out)[t] = o;
    }
}

extern "C" void kernel_launch(void* const* d_in, const int* in_sizes, int n_in,
                              void* d_out, int out_size, void* d_ws, size_t ws_size,
                              hipStream_t stream) {
    const float* x     = (const float*)d_in[0];
    const float* gamma = (const float*)d_in[1];
    const float* beta  = (const float*)d_in[2];
    float* out = (float*)d_out;

    const int bsz = in_sizes[0] / 784;

    double* acc = (double*)d_ws;
    float*  z   = (float*)((char*)d_ws + 1024);

    hipMemsetAsync(d_ws, 0, 64, stream);

    qnat_stage1<<<(bsz + 31) / 32, 256, 0, stream>>>(x, z, acc, bsz);
    qnat_stage2<<<(bsz + 255) / 256, 256, 0, stream>>>(z, acc, gamma, beta, out, bsz);
}

// Round 3
// 45.739 us; speedup vs baseline: 1.8357x; 1.8357x over previous
//
#include <hip/hip_runtime.h>

#define EPS 1e-5f

// Math: theta_p = mean(x[b,0,6p:6p+6,0:6]); c_p = cos(theta_p);
// CNOT chain (0,1)(1,2)(2,3)(3,0) is a classical XOR map =>
// z0=c1*c2*c3, z1=c0*c1, z2=c0*c1*c2, z3=c0*c1*c2*c3; then batchnorm over B.
//
// ws layout:
//   [0, 32)                     float stats[8] = {mean[4], scale[4]}  (scale = gamma*rsqrt(var+eps))
//   [4096, 4096+bsz*16)         float z[bsz][4]
//   [4096+bsz*16, +NB*32)       float partials[NB][8] = {sum[4], sumsq[4]}  (NB = ceil(bsz/16))

__global__ __launch_bounds__(256) void qnat_k1(const float* __restrict__ x,
                                               float* __restrict__ z_out,
                                               float* __restrict__ partials,
                                               int bsz) {
    const int t    = threadIdx.x;
    const int lane = t & 63;
    const int w    = t >> 6;           // wave 0..3
    const int imgBase = blockIdx.x * 16;

    float s1[4] = {0.f, 0.f, 0.f, 0.f};
    float s2[4] = {0.f, 0.f, 0.f, 0.f};

    #pragma unroll
    for (int iter = 0; iter < 4; ++iter) {
        const int img = imgBase + iter * 4 + w;   // one image per wave
        float a0 = 0.f, a1 = 0.f, a2 = 0.f, a3 = 0.f;
        if (img < bsz) {
            const float* ip = x + (size_t)img * 784;
            #pragma unroll
            for (int r = 0; r < 3; ++r) {
                const int j = r * 64 + lane;              // float4 index, 0..191 (16*191+16 <= 3136)
                const float4 v = *reinterpret_cast<const float4*>(ip + 4 * j);
                const int m = j % 7;                      // col-phase: only 0,1 contribute
                const int p = j / 42;                     // theta index (4 => padding, dropped)
                float contrib = 0.f;
                if (m == 0)      contrib = (v.x + v.y) + (v.z + v.w);   // cols 0-3
                else if (m == 1) contrib = v.x + v.y;                   // cols 4-5
                a0 += (p == 0) ? contrib : 0.f;
                a1 += (p == 1) ? contrib : 0.f;
                a2 += (p == 2) ? contrib : 0.f;
                a3 += (p == 3) ? contrib : 0.f;
            }
        }
        // full-wave butterfly reduce: every lane ends with the 36-elem row sums
        #pragma unroll
        for (int off = 1; off < 64; off <<= 1) {
            a0 += __shfl_xor(a0, off, 64);
            a1 += __shfl_xor(a1, off, 64);
            a2 += __shfl_xor(a2, off, 64);
            a3 += __shfl_xor(a3, off, 64);
        }
        const float k = 1.0f / 36.0f;
        const float c0 = cosf(a0 * k), c1 = cosf(a1 * k);
        const float c2 = cosf(a2 * k), c3 = cosf(a3 * k);
        const float z1 = c0 * c1;
        const float z2 = z1 * c2;
        const float z3 = z2 * c3;
        const float z0 = c1 * c2 * c3;
        if (img < bsz) {
            if (lane == 0) {
                float4 zz; zz.x = z0; zz.y = z1; zz.z = z2; zz.w = z3;
                *reinterpret_cast<float4*>(z_out + (size_t)img * 4) = zz;
            }
            s1[0] += z0; s1[1] += z1; s1[2] += z2; s1[3] += z3;
            s2[0] += z0 * z0; s2[1] += z1 * z1; s2[2] += z2 * z2; s2[3] += z3 * z3;
        }
    }

    // combine 4 waves' (identical-per-lane) partials -> 8 floats per block, no atomics
    __shared__ float ps[4][8];
    if (lane == 0) {
        #pragma unroll
        for (int k = 0; k < 4; ++k) { ps[w][k] = s1[k]; ps[w][4 + k] = s2[k]; }
    }
    __syncthreads();
    if (t < 8) {
        partials[blockIdx.x * 8 + t] =
            (ps[0][t] + ps[1][t]) + (ps[2][t] + ps[3][t]);
    }
}

__global__ __launch_bounds__(1024) void qnat_stats(const float* __restrict__ partials,
                                                   const float* __restrict__ gamma,
                                                   float* __restrict__ stats,
                                                   int NB, int bsz) {
    const int t = threadIdx.x;
    float acc[8] = {0.f,0.f,0.f,0.f,0.f,0.f,0.f,0.f};
    for (int r = t; r < NB; r += 1024) {
        const float4 a = *reinterpret_cast<const float4*>(partials + r * 8);
        const float4 b = *reinterpret_cast<const float4*>(partials + r * 8 + 4);
        acc[0] += a.x; acc[1] += a.y; acc[2] += a.z; acc[3] += a.w;
        acc[4] += b.x; acc[5] += b.y; acc[6] += b.z; acc[7] += b.w;
    }
    #pragma unroll
    for (int off = 1; off < 64; off <<= 1)
        #pragma unroll
        for (int k = 0; k < 8; ++k) acc[k] += __shfl_xor(acc[k], off, 64);

    __shared__ float ls[16][8];
    const int wv = t >> 6, lane = t & 63;
    if (lane == 0)
        #pragma unroll
        for (int k = 0; k < 8; ++k) ls[wv][k] = acc[k];
    __syncthreads();
    if (t < 8) {
        float tot = 0.f;
        #pragma unroll
        for (int v = 0; v < 16; ++v) tot += ls[v][t];
        ls[0][t] = tot;                 // reuse LDS for totals
    }
    __syncthreads();
    if (t < 4) {
        const double invB = 1.0 / (double)bsz;
        const double m = (double)ls[0][t] * invB;
        const double var = (double)ls[0][4 + t] * invB - m * m;
        stats[t]     = (float)m;
        stats[4 + t] = gamma[t] * rsqrtf((float)var + EPS);
    }
}

__global__ __launch_bounds__(256) void qnat_k2(const float* __restrict__ z,
                                               const float* __restrict__ stats,
                                               const float* __restrict__ beta,
                                               float* __restrict__ out,
                                               int bsz) {
    const int t = blockIdx.x * blockDim.x + threadIdx.x;
    if (t < bsz) {
        const float4 zv = reinterpret_cast<const float4*>(z)[t];
        float4 o;
        o.x = (zv.x - stats[0]) * stats[4] + beta[0];
        o.y = (zv.y - stats[1]) * stats[5] + beta[1];
        o.z = (zv.z - stats[2]) * stats[6] + beta[2];
        o.w = (zv.w - stats[3]) * stats[7] + beta[3];
        reinterpret_cast<float4*>(out)[t] = o;
    }
}

extern "C" void kernel_launch(void* const* d_in, const int* in_sizes, int n_in,
                              void* d_out, int out_size, void* d_ws, size_t ws_size,
                              hipStream_t stream) {
    const float* x     = (const float*)d_in[0];
    const float* gamma = (const float*)d_in[1];
    const float* beta  = (const float*)d_in[2];
    float* out = (float*)d_out;

    const int bsz = in_sizes[0] / 784;
    const int NB  = (bsz + 15) / 16;

    float* stats    = (float*)d_ws;
    float* z        = (float*)((char*)d_ws + 4096);
    float* partials = (float*)((char*)d_ws + 4096 + (size_t)bsz * 16);

    qnat_k1   <<<NB, 256, 0, stream>>>(x, z, partials, bsz);
    qnat_stats<<<1, 1024, 0, stream>>>(partials, gamma, stats, NB, bsz);
    qnat_k2   <<<(bsz + 255) / 256, 256, 0, stream>>>(z, stats, beta, out, bsz);
}